// Round 1
// 128.525 us; speedup vs baseline: 1.0256x; 1.0256x over previous
//
#include <hip/hip_runtime.h>

// x (8,320,320) f32, u (8,12,320,320,2) f32 -> out (8,12,320,320) f32.
//
// R1 theory: kernel portion (~37us of the 131.8us graph; the rest is two
// ~47us harness poison fills) is HBM-bound (121 MB min => ~19us) but runs
// 2 scheduling epochs because grid=1200 blocks vs 1024 resident (4/CU).
// Fix: 4x more, 4x smaller blocks (TILE 32, 4800 blocks => ~7% tail
// overhead instead of ~70%). Also: single f32 LDS copy (same 17KB LDS as
// the old dual-fp16 scheme, fewer instructions, exact results).
#define PP 8
#define FF 12
#define MM 320
#define NN 320
#define TILE 32
#define HALO 16
#define LW   (TILE + 2 * HALO)   // 64 staged rows/cols
#define PW   68                  // padded row stride in words: 64 data + 4 pad
                                 // (keeps rows 16B-aligned for b128 stores,
                                 //  skews banks by 4 per row)
#define FPB  2                   // frames per block

typedef float fvec4 __attribute__((ext_vector_type(4)));
typedef float fvec2 __attribute__((ext_vector_type(2)));

__global__ __launch_bounds__(512, 8) void warp_tile_kernel(
    const float* __restrict__ x,
    const float* __restrict__ u,
    float* __restrict__ out)
{
    __shared__ float tile[LW * PW];        // 17,408 B -> 4 blocks/CU (thread-capped)

    int zz = blockIdx.z;                   // p * 6 + fgroup
    int p  = zz / (FF / FPB);
    int f0 = (zz % (FF / FPB)) * FPB;
    int i0 = blockIdx.y * TILE;
    int j0 = blockIdx.x * TILE;

    const float* __restrict__ img = x + p * (MM * NN);

    // Stage 64x64 f32 tile, zero outside image. Col 4-groups are 16B-aligned
    // and fully in or out of the image (NN%4==0, offsets %4==0).
    // 64*16 = 1024 vec4 groups / 512 threads = exactly 2 iterations.
#pragma unroll
    for (int it = 0; it < 2; ++it) {
        int idx = (int)threadIdx.x + it * 512;
        int r  = idx >> 4;                 // 0..63
        int c4 = idx & 15;                 // 0..15
        int gr = i0 - HALO + r;
        int gc = j0 - HALO + c4 * 4;
        fvec4 v = {0.0f, 0.0f, 0.0f, 0.0f};
        if ((unsigned)gr < MM && (unsigned)gc < NN)
            v = *(const fvec4*)(img + gr * NN + gc);
        *(fvec4*)&tile[r * PW + c4 * 4] = v;   // row stride 272 B, 16B aligned
    }
    __syncthreads();

    // Thread layout: 2 consecutive cols x 1 row; wave covers 32 cols x 4 rows.
    int tcol = ((int)threadIdx.x & 15) * 2;    // 0..30
    int row0 = ((int)threadIdx.x >> 4);        // 0..31
    int gi = i0 + row0;
    int gj = j0 + tcol;

#pragma unroll
    for (int ff = 0; ff < FPB; ++ff) {
        int pf = p * FF + (f0 + ff);
        const float* __restrict__ ubase = u + (size_t)pf * (MM * NN * 2);
        float* __restrict__ obase = out + (size_t)pf * (MM * NN);

        // 2 pixels/thread/frame: one 16B u-load = (dx0,dy0,dx1,dy1).
        fvec4 ua = *(const fvec4*)(ubase + 2 * ((size_t)gi * NN + gj));
        float dx[2] = {ua.x, ua.z};
        float dy[2] = {ua.y, ua.w};

        float res[2];
#pragma unroll
        for (int k = 0; k < 2; ++k) {
            float sx = (float)(gj + k) + dx[k];
            float sy = (float)gi + dy[k];
            float fx0 = floorf(sx);
            float fy0 = floorf(sy);
            float wx = sx - fx0;
            float wy = sy - fy0;
            int x0i = (int)fx0;
            int y0i = (int)fy0;

            int lx = x0i - (j0 - HALO);
            int ly = y0i - (i0 - HALO);

            float v00, v01, v10, v11;
            if (((unsigned)lx < (LW - 1)) & ((unsigned)ly < (LW - 1))) {
                // 4 corners = 2x ds_read2_b32 (offsets 0/1 and 68/69).
                const float* t = &tile[ly * PW + lx];
                v00 = t[0];
                v01 = t[1];
                v10 = t[PW];
                v11 = t[PW + 1];
            } else {
                // Rare (|flow| >= halo, ~1e-4 of pixels): predicated global
                // gather, x is L2-resident.
                int xc0 = min(max(x0i,     0), NN - 1);
                int xc1 = min(max(x0i + 1, 0), NN - 1);
                int yc0 = min(max(y0i,     0), MM - 1);
                int yc1 = min(max(y0i + 1, 0), MM - 1);
                bool vx0 = (x0i >= 0)     & (x0i < NN);
                bool vx1 = (x0i + 1 >= 0) & (x0i + 1 < NN);
                bool vy0 = (y0i >= 0)     & (y0i < MM);
                bool vy1 = (y0i + 1 >= 0) & (y0i + 1 < MM);
                int r0i = yc0 * NN;
                int r1i = yc1 * NN;
                v00 = (vy0 & vx0) ? img[r0i + xc0] : 0.0f;
                v01 = (vy0 & vx1) ? img[r0i + xc1] : 0.0f;
                v10 = (vy1 & vx0) ? img[r1i + xc0] : 0.0f;
                v11 = (vy1 & vx1) ? img[r1i + xc1] : 0.0f;
            }

            float vt = fmaf(wx, v01 - v00, v00);
            float vb = fmaf(wx, v11 - v10, v10);
            res[k] = fmaf(wy, vb - vt, vt);
        }

        fvec2 o = {res[0], res[1]};
        __builtin_nontemporal_store(o, (fvec2*)(obase + (size_t)gi * NN + gj));
    }
}

extern "C" void kernel_launch(void* const* d_in, const int* in_sizes, int n_in,
                              void* d_out, int out_size, void* d_ws, size_t ws_size,
                              hipStream_t stream) {
    const float* x = (const float*)d_in[0];
    const float* u = (const float*)d_in[1];
    float* out = (float*)d_out;

    dim3 grid(NN / TILE, MM / TILE, PP * (FF / FPB));  // 10 x 10 x 48 = 4800 blocks
    dim3 block(512);
    warp_tile_kernel<<<grid, block, 0, stream>>>(x, u, out);
}